// Round 6
// baseline (4662.351 us; speedup 1.0000x reference)
//
#include <hip/hip_runtime.h>
#include <hip/hip_bf16.h>

// Problem constants (LSTM_Layer_48601849922172)
#define B_  32
#define T_  512
#define I_  1024
#define H_  1024
#define G4_ 4096   // 4*H
#define NWG 32     // persistent workgroups

typedef short short8 __attribute__((ext_vector_type(8)));   // 8 bf16 in 4 VGPRs
typedef float f32x4  __attribute__((ext_vector_type(4)));

__device__ __forceinline__ ushort f2bf(float f) {
    unsigned u = __builtin_bit_cast(unsigned, f);
    u += 0x7fffu + ((u >> 16) & 1u);   // RNE
    return (ushort)(u >> 16);
}
__device__ __forceinline__ float bf2f(ushort u) {
    unsigned x = ((unsigned)u) << 16;
    return __builtin_bit_cast(float, x);
}

__device__ __forceinline__ void async16(const void* g, void* l) {
    __builtin_amdgcn_global_load_lds((const __attribute__((address_space(1))) void*)g,
                                     (__attribute__((address_space(3))) void*)l,
                                     16, 0, 0);
}

// ---------------- f32 -> bf16 conversion (vectorized, grid-stride) -------------
__global__ void cvt_bf16(const float* __restrict__ in, ushort* __restrict__ out, int n) {
    int stride = gridDim.x * blockDim.x;
    for (int i = blockIdx.x * blockDim.x + threadIdx.x; i * 4 < n; i += stride) {
        float4 v = reinterpret_cast<const float4*>(in)[i];
        ushort4 o;
        o.x = f2bf(v.x); o.y = f2bf(v.y); o.z = f2bf(v.z); o.w = f2bf(v.w);
        reinterpret_cast<ushort4*>(out)[i] = o;
    }
}

// ---------------- wx = x @ W^T + b_w : m97-style 128x128x32 MFMA GEMM ----------
// A: [M][K] bf16 (M = B*T, row = b*T + t), Bm: [N][K] bf16 (W, B^T layout).
// Output: bf16, remapped to [T][B][4H] so each step's slice is contiguous.
#define BM 128
#define BN 128
#define BK 32

__global__ __launch_bounds__(256) void gemm_bt(
    const ushort* __restrict__ A, const ushort* __restrict__ Bm,
    const float* __restrict__ bias, ushort* __restrict__ C,
    int M, int N, int K)
{
    __shared__ ushort sA[2][BM * BK];
    __shared__ ushort sB[2][BN * BK];

    const int tid  = threadIdx.x;
    const int m0   = blockIdx.y * BM;
    const int n0   = blockIdx.x * BN;
    const int lane = tid & 63, wid = tid >> 6;
    const int wm   = (wid >> 1) * 64, wn = (wid & 1) * 64;
    const int lr   = lane & 15, lg = lane >> 4;

    f32x4 acc[4][4] = {};

    auto stage = [&](int buf, int kt) {
        const int k0 = kt * BK;
#pragma unroll
        for (int i = 0; i < 2; ++i) {
            int c = tid + i * 256;                 // 512 chunks of 16B per tile
            const ushort* ga = A  + (size_t)(m0 + (c >> 2)) * K + k0 + (c & 3) * 8;
            async16(ga, &sA[buf][c * 8]);
            const ushort* gb = Bm + (size_t)(n0 + (c >> 2)) * K + k0 + (c & 3) * 8;
            async16(gb, &sB[buf][c * 8]);
        }
    };

    stage(0, 0);
    __syncthreads();

    const int nk = K / BK;
    int buf = 0;
    for (int kt = 0; kt < nk; ++kt) {
        if (kt + 1 < nk) stage(buf ^ 1, kt + 1);
        short8 af[4], bfr[4];
#pragma unroll
        for (int i = 0; i < 4; ++i)
            af[i]  = *reinterpret_cast<const short8*>(&sA[buf][(wm + i * 16 + lr) * BK + lg * 8]);
#pragma unroll
        for (int i = 0; i < 4; ++i)
            bfr[i] = *reinterpret_cast<const short8*>(&sB[buf][(wn + i * 16 + lr) * BK + lg * 8]);
#pragma unroll
        for (int mi = 0; mi < 4; ++mi)
#pragma unroll
            for (int ni = 0; ni < 4; ++ni)
                acc[mi][ni] = __builtin_amdgcn_mfma_f32_16x16x32_bf16(af[mi], bfr[ni], acc[mi][ni], 0, 0, 0);
        __syncthreads();
        buf ^= 1;
    }

    // C/D layout (m89-verified): col = lane&15, row = (lane>>4)*4 + reg
#pragma unroll
    for (int mi = 0; mi < 4; ++mi) {
#pragma unroll
        for (int ni = 0; ni < 4; ++ni) {
            int col = n0 + wn + ni * 16 + lr;
            float bv = bias[col];
#pragma unroll
            for (int r = 0; r < 4; ++r) {
                int row = m0 + wm + mi * 16 + lg * 4 + r;   // = b*T + t
                int b = row >> 9, t = row & (T_ - 1);
                C[((size_t)t * B_ + b) * G4_ + col] = f2bf(acc[mi][ni][r] + bv);
            }
        }
    }
}

// ---------------- persistent recurrence -----------------------------------------
// 32 WGs x 512 threads (8 waves), all resident (<= 256 CUs -> no deadlock).
// WG j owns h-cols [j*32, j*32+32). Wave w: gate g = w&3, col-half hh = w>>2.
// U held in VGPRs (short8 ureg[32] = 128 VGPRs/lane, statically indexed).
// Per step: grid barrier (monotone counter, s_sleep backoff) -> stage h (64KB,
// global_load_lds, linear dest + inverse-XOR source) -> 64 MFMA/wave (B from
// regs, A from LDS with matching XOR swizzle) -> gates in LDS -> pointwise
// (c in regs) -> write h ping-pong + hs/cs -> fence + arrive.
__global__ __launch_bounds__(512, 2) void lstm_persist(
    const ushort* __restrict__ wx,     // [T][B][4H] bf16
    const ushort* __restrict__ U_bf,   // [4H][H] bf16
    const float*  __restrict__ b_u,    // [4H]
    ushort* __restrict__ hb0,          // [B][H] bf16 ping
    ushort* __restrict__ hb1,          // [B][H] bf16 pong
    float*  __restrict__ hs,           // [B][T][H]
    float*  __restrict__ cs,           // [B][T][H]
    unsigned* __restrict__ cnt)        // grid barrier counter (pre-zeroed)
{
    const int tid = threadIdx.x;
    const int lane = tid & 63, wid = tid >> 6;
    const int lr = lane & 15, lg = lane >> 4;
    const int g = wid & 3, hh = wid >> 2;
    const int j = blockIdx.x;
    const int colh = j * 32 + hh * 16 + lr;     // h-column of this lane's tile
    const int colg = g * H_ + colh;             // gate column

    // U slice into registers: lane covers k = k0+lg*8 .. +8 for k0 = 0,32,..,992
    short8 ureg[32];
    {
        const ushort* up = U_bf + (size_t)colg * H_ + lg * 8;
#pragma unroll
        for (int k = 0; k < 32; ++k)
            ureg[k] = *reinterpret_cast<const short8*>(up + k * 32);
    }
    const float bu = b_u[colg];

    __shared__ ushort sh[32 * 1024];       // h tile [B][H] bf16, XOR-swizzled (64KB)
    __shared__ float  gates[4][32][32];    // [gate][batch][local col] (16KB)

    // pointwise mapping: elem0 = (b0p, ci0), elem1 = (16+b0p, ci0); c in regs
    const int b0p = tid >> 5, ci0 = tid & 31;
    float creg0 = 0.f, creg1 = 0.f;

    for (int t = 0; t < T_; ++t) {
        if (t > 0) {
            // ---- grid barrier: wait until all NWG arrived for step t-1 ----
            if (tid == 0) {
                while (atomicAdd(cnt, 0u) < (unsigned)(NWG * t)) {
                    __builtin_amdgcn_s_sleep(2);   // backoff: ~128 cy between polls
                }
                __threadfence();           // acquire: invalidate stale L1/L2
            }
            __syncthreads();

            // ---- stage h_{t-1} -> LDS (linear dest, inverse-XOR'd source) ----
            const char* hpc = (const char*)((t & 1) ? hb0 : hb1);  // h_{t-1} = hb[(t-1)&1]
#pragma unroll
            for (int i = 0; i < 8; ++i) {
                int o = (i * 512 + tid) * 16;          // LDS byte offset (linear)
                int row = o >> 11, inner = o & 2047;
                int si = inner ^ ((row & 7) << 4);     // inverse swizzle (involution)
                async16(hpc + row * 2048 + si, ((char*)sh) + o);
            }
            __syncthreads();   // drains vmcnt per-wave before any sh read

            // ---- gates tile: h @ U^T via MFMA (B-operand from ureg) ----
            f32x4 acc0 = {}, acc1 = {};
            const char* shc = (const char*)sh;
            const int sw = (lr & 7) << 4;
            const int base0 = lr * 2048, base1 = (16 + lr) * 2048;
#pragma unroll
            for (int k = 0; k < 32; ++k) {
                int cb = (k * 32 + lg * 8) * 2;
                short8 a0 = *reinterpret_cast<const short8*>(shc + base0 + (cb ^ sw));
                short8 a1 = *reinterpret_cast<const short8*>(shc + base1 + (cb ^ sw));
                acc0 = __builtin_amdgcn_mfma_f32_16x16x32_bf16(a0, ureg[k], acc0, 0, 0, 0);
                acc1 = __builtin_amdgcn_mfma_f32_16x16x32_bf16(a1, ureg[k], acc1, 0, 0, 0);
            }
            const ushort* wxt = wx + (size_t)t * B_ * G4_;
#pragma unroll
            for (int r = 0; r < 4; ++r) {
                gates[g][lg * 4 + r][hh * 16 + lr] =
                    acc0[r] + bf2f(wxt[(lg * 4 + r) * G4_ + colg]) + bu;
                gates[g][16 + lg * 4 + r][hh * 16 + lr] =
                    acc1[r] + bf2f(wxt[(16 + lg * 4 + r) * G4_ + colg]) + bu;
            }
        } else {
            // t == 0: h_{-1} = 0 -> gates = wx + b_u
            const ushort* wxt = wx;
#pragma unroll
            for (int r = 0; r < 4; ++r) {
                gates[g][lg * 4 + r][hh * 16 + lr] =
                    bf2f(wxt[(lg * 4 + r) * G4_ + colg]) + bu;
                gates[g][16 + lg * 4 + r][hh * 16 + lr] =
                    bf2f(wxt[(16 + lg * 4 + r) * G4_ + colg]) + bu;
            }
        }
        __syncthreads();

        // ---- pointwise: 2 (b, col) elements per thread, c in registers ----
        ushort* hn = (t & 1) ? hb1 : hb0;     // h_t -> hb[t&1]
        {
            int col = j * 32 + ci0;
            float gi = gates[0][b0p][ci0], gf = gates[1][b0p][ci0];
            float gg = gates[2][b0p][ci0], go = gates[3][b0p][ci0];
            float si = 1.f / (1.f + __expf(-gi));
            float sf = 1.f / (1.f + __expf(-gf));
            float so = 1.f / (1.f + __expf(-go));
            float tg = 2.f / (1.f + __expf(-2.f * gg)) - 1.f;
            float c  = sf * creg0 + si * tg;  creg0 = c;
            float h  = so * fmaxf(c, 0.f);
            hn[b0p * H_ + col] = f2bf(h);
            hs[((size_t)b0p * T_ + t) * H_ + col] = h;
            cs[((size_t)b0p * T_ + t) * H_ + col] = c;

            int b1 = 16 + b0p;
            gi = gates[0][b1][ci0]; gf = gates[1][b1][ci0];
            gg = gates[2][b1][ci0]; go = gates[3][b1][ci0];
            si = 1.f / (1.f + __expf(-gi));
            sf = 1.f / (1.f + __expf(-gf));
            so = 1.f / (1.f + __expf(-go));
            tg = 2.f / (1.f + __expf(-2.f * gg)) - 1.f;
            c  = sf * creg1 + si * tg;  creg1 = c;
            h  = so * fmaxf(c, 0.f);
            hn[b1 * H_ + col] = f2bf(h);
            hs[((size_t)b1 * T_ + t) * H_ + col] = h;
            cs[((size_t)b1 * T_ + t) * H_ + col] = c;
        }

        // ---- arrive: syncthreads drains every wave's stores to L2,
        //      thread0's release fence writes the XCD L2 back ----
        __syncthreads();
        if (tid == 0) {
            __threadfence();
            atomicAdd(cnt, 1u);
        }
    }
}

// ------------------------------- launcher --------------------------------------
extern "C" void kernel_launch(void* const* d_in, const int* in_sizes, int n_in,
                              void* d_out, int out_size, void* d_ws, size_t ws_size,
                              hipStream_t stream)
{
    const float* x  = (const float*)d_in[0];   // [B,T,I]
    const float* W  = (const float*)d_in[1];   // [4H,I]
    const float* bw = (const float*)d_in[2];   // [4H]
    const float* Uf = (const float*)d_in[3];   // [4H,H]
    const float* bu = (const float*)d_in[4];   // [4H]

    float* out = (float*)d_out;
    float* hs  = out;                          // [B,T,H]
    float* cs  = out + (size_t)B_ * T_ * H_;   // [B,T,H]

    char* ws = (char*)d_ws;
    ushort*  x_bf  = (ushort*)ws;                            // 32 MiB @ 0
    ushort*  W_bf  = (ushort*)(ws + 33554432);               // 8 MiB
    ushort*  U_bf  = (ushort*)(ws + 41943040);               // 8 MiB
    ushort*  wx_bf = (ushort*)(ws + 50331648);               // 128 MiB [T][B][4H]
    ushort*  hb0   = (ushort*)(ws + 184549376);              // 64 KiB
    ushort*  hb1   = (ushort*)(ws + 184614912);              // 64 KiB
    unsigned* cnt  = (unsigned*)(ws + 184680448);            // 256 B

    hipMemsetAsync(cnt, 0, 256, stream);   // barrier counter must start at 0

    cvt_bf16<<<2048, 256, 0, stream>>>(x,  x_bf, B_ * T_ * I_);
    cvt_bf16<<<1024, 256, 0, stream>>>(W,  W_bf, G4_ * I_);
    cvt_bf16<<<1024, 256, 0, stream>>>(Uf, U_bf, G4_ * H_);

    dim3 grid(G4_ / BN, (B_ * T_) / BM);   // 32 x 128
    gemm_bt<<<grid, 256, 0, stream>>>(x_bf, W_bf, bw, wx_bf, B_ * T_, G4_, I_);

    lstm_persist<<<NWG, 512, 0, stream>>>(wx_bf, U_bf, bu, hb0, hb1, hs, cs, cnt);
}

// Round 7
// 4018.134 us; speedup vs baseline: 1.1603x; 1.1603x over previous
//
#include <hip/hip_runtime.h>
#include <hip/hip_bf16.h>

// Problem constants (LSTM_Layer_48601849922172)
#define B_  32
#define T_  512
#define I_  1024
#define H_  1024
#define G4_ 4096   // 4*H
#define NWG 32     // persistent workgroups

typedef short short8 __attribute__((ext_vector_type(8)));   // 8 bf16 in 4 VGPRs
typedef float f32x4  __attribute__((ext_vector_type(4)));

__device__ __forceinline__ ushort f2bf(float f) {
    unsigned u = __builtin_bit_cast(unsigned, f);
    u += 0x7fffu + ((u >> 16) & 1u);   // RNE
    return (ushort)(u >> 16);
}
__device__ __forceinline__ float bf2f(ushort u) {
    unsigned x = ((unsigned)u) << 16;
    return __builtin_bit_cast(float, x);
}

__device__ __forceinline__ void async16(const void* g, void* l) {
    __builtin_amdgcn_global_load_lds((const __attribute__((address_space(1))) void*)g,
                                     (__attribute__((address_space(3))) void*)l,
                                     16, 0, 0);
}

// ---------------- f32 -> bf16 conversion (vectorized, grid-stride) -------------
__global__ void cvt_bf16(const float* __restrict__ in, ushort* __restrict__ out, int n) {
    int stride = gridDim.x * blockDim.x;
    for (int i = blockIdx.x * blockDim.x + threadIdx.x; i * 4 < n; i += stride) {
        float4 v = reinterpret_cast<const float4*>(in)[i];
        ushort4 o;
        o.x = f2bf(v.x); o.y = f2bf(v.y); o.z = f2bf(v.z); o.w = f2bf(v.w);
        reinterpret_cast<ushort4*>(out)[i] = o;
    }
}

// ---------------- wx = x @ W^T + b_w : m97-style 128x128x32 MFMA GEMM ----------
// A: [M][K] bf16 (M = B*T, row = b*T + t), Bm: [N][K] bf16 (W, B^T layout).
// Output: bf16, remapped to [T][B][4H] so each step's slice is contiguous.
#define BM 128
#define BN 128
#define BK 32

__global__ __launch_bounds__(256) void gemm_bt(
    const ushort* __restrict__ A, const ushort* __restrict__ Bm,
    const float* __restrict__ bias, ushort* __restrict__ C,
    int M, int N, int K)
{
    __shared__ ushort sA[2][BM * BK];
    __shared__ ushort sB[2][BN * BK];

    const int tid  = threadIdx.x;
    const int m0   = blockIdx.y * BM;
    const int n0   = blockIdx.x * BN;
    const int lane = tid & 63, wid = tid >> 6;
    const int wm   = (wid >> 1) * 64, wn = (wid & 1) * 64;
    const int lr   = lane & 15, lg = lane >> 4;

    f32x4 acc[4][4] = {};

    auto stage = [&](int buf, int kt) {
        const int k0 = kt * BK;
#pragma unroll
        for (int i = 0; i < 2; ++i) {
            int c = tid + i * 256;                 // 512 chunks of 16B per tile
            const ushort* ga = A  + (size_t)(m0 + (c >> 2)) * K + k0 + (c & 3) * 8;
            async16(ga, &sA[buf][c * 8]);
            const ushort* gb = Bm + (size_t)(n0 + (c >> 2)) * K + k0 + (c & 3) * 8;
            async16(gb, &sB[buf][c * 8]);
        }
    };

    stage(0, 0);
    __syncthreads();

    const int nk = K / BK;
    int buf = 0;
    for (int kt = 0; kt < nk; ++kt) {
        if (kt + 1 < nk) stage(buf ^ 1, kt + 1);
        short8 af[4], bfr[4];
#pragma unroll
        for (int i = 0; i < 4; ++i)
            af[i]  = *reinterpret_cast<const short8*>(&sA[buf][(wm + i * 16 + lr) * BK + lg * 8]);
#pragma unroll
        for (int i = 0; i < 4; ++i)
            bfr[i] = *reinterpret_cast<const short8*>(&sB[buf][(wn + i * 16 + lr) * BK + lg * 8]);
#pragma unroll
        for (int mi = 0; mi < 4; ++mi)
#pragma unroll
            for (int ni = 0; ni < 4; ++ni)
                acc[mi][ni] = __builtin_amdgcn_mfma_f32_16x16x32_bf16(af[mi], bfr[ni], acc[mi][ni], 0, 0, 0);
        __syncthreads();
        buf ^= 1;
    }

    // C/D layout (m89-verified): col = lane&15, row = (lane>>4)*4 + reg
#pragma unroll
    for (int mi = 0; mi < 4; ++mi) {
#pragma unroll
        for (int ni = 0; ni < 4; ++ni) {
            int col = n0 + wn + ni * 16 + lr;
            float bv = bias[col];
#pragma unroll
            for (int r = 0; r < 4; ++r) {
                int row = m0 + wm + mi * 16 + lg * 4 + r;   // = b*T + t
                int b = row >> 9, t = row & (T_ - 1);
                C[((size_t)t * B_ + b) * G4_ + col] = f2bf(acc[mi][ni][r] + bv);
            }
        }
    }
}

// ---------------- persistent recurrence -----------------------------------------
// 32 WGs x 512 threads. WG j owns h-cols [j*32, j*32+32) for all 4 gates.
// Wave w: gate g = w&3, k-half kh = w>>2 (k-split cuts per-wave LDS A-reads 4x;
// partials reduced through a swizzled LDS tile).
// U fragments pinned in VGPRs via one-time volatile loads (anti-rematerialization).
// Cross-step h exchange: relaxed AGENT-scope atomics (coherence-point access,
// no cache-wide wbl2/inv fences). hs/cs: nontemporal stores after the arrive.
__global__ __launch_bounds__(512, 2) void lstm_persist(
    const ushort* __restrict__ wx,     // [T][B][4H] bf16
    const ushort* U_bf,                // [4H][H] bf16 (no restrict: keep loads early)
    const float*  __restrict__ b_u,    // [4H]
    uint*   __restrict__ hbuf,         // [2][32][512] uint (2 bf16 packed) ping-pong
    float*  __restrict__ hs,           // [B][T][H]
    float*  __restrict__ cs,           // [B][T][H]
    unsigned* cnt)                     // grid barrier counter (pre-zeroed)
{
    const int tid  = threadIdx.x;
    const int lane = tid & 63, wid = tid >> 6;
    const int lr   = lane & 15, lg = lane >> 4;
    const int g    = wid & 3, kh = wid >> 2;
    const int j    = blockIdx.x;

    // ---- U fragments -> VGPRs (volatile: cannot be sunk/rematerialized) ----
    // wave (g,kh), lane (lr,lg): frag (n,s) = U[g*1024+j*32+n*16+lr][kh*512+s*32+lg*8 ..+8]
    short8 ureg[2][16];
#pragma unroll
    for (int n = 0; n < 2; ++n)
#pragma unroll
        for (int s = 0; s < 16; ++s) {
            const volatile uint* p =
                (const volatile uint*)(U_bf + (size_t)(g * 1024 + j * 32 + n * 16 + lr) * 1024
                                       + kh * 512 + s * 32 + lg * 8);
            uint4 w; w.x = p[0]; w.y = p[1]; w.z = p[2]; w.w = p[3];
            ureg[n][s] = __builtin_bit_cast(short8, w);
        }

    __shared__ ushort sh[32 * 1024];        // 64KB h tile, XOR-swizzled rows
    __shared__ float  gpart[2][4][32][32];  // 32KB [kh][g][col][b^swz] partial gates
    __shared__ ushort swx[2][4096];         // 2x8KB wx tile [buf][b][g][32 cols]
    char* shc = (char*)sh;

    // pointwise mapping: thread -> (batch bp, col pair cp, cp+1); c-state in regs
    const int bp = tid >> 4, cp = (tid & 15) * 2;
    float creg[2] = {0.f, 0.f};
    float bu2[4][2];
#pragma unroll
    for (int g2 = 0; g2 < 4; ++g2) {
        bu2[g2][0] = b_u[g2 * 1024 + j * 32 + cp];
        bu2[g2][1] = b_u[g2 * 1024 + j * 32 + cp + 1];
    }

    // wx prefetch: 8KB/WG/step -> LDS via global_load_lds (linear dest)
    auto prefetch_wx = [&](int tt, int buf) {
        int b = tid >> 4, g2 = (tid >> 2) & 3, q = tid & 3;
        const ushort* src = wx + ((size_t)tt * 32 + b) * 4096 + g2 * 1024 + j * 32 + q * 8;
        async16(src, (char*)swx + buf * 8192 + tid * 16);
    };

    prefetch_wx(0, 0);

    for (int t = 0; t < T_; ++t) {
        if (t > 0) {
            // ---- wait for all WGs to finish step t-1 ----
            if (tid == 0) {
                while (__hip_atomic_load(cnt, __ATOMIC_RELAXED, __HIP_MEMORY_SCOPE_AGENT)
                       < (unsigned)(NWG * t))
                    __builtin_amdgcn_s_sleep(1);
            }
            __syncthreads();                                  // B1

            // ---- stage h_{t-1}: coherent 8B loads -> swizzled LDS ----
            const unsigned long long* hsrc =
                (const unsigned long long*)(hbuf + ((t + 1) & 1) * 16384);
#pragma unroll
            for (int i = 0; i < 16; ++i) {
                int idx = i * 512 + tid;
                unsigned long long v = __hip_atomic_load(&hsrc[idx],
                    __ATOMIC_RELAXED, __HIP_MEMORY_SCOPE_AGENT);
                int o = idx * 8, row = o >> 11, inner = o & 2047;
                *(unsigned long long*)(shc + row * 2048 + (inner ^ ((row & 7) << 4))) = v;
            }
            __syncthreads();                                  // B2

            prefetch_wx(t + 1 < T_ ? t + 1 : t, (t + 1) & 1); // latency hidden by MFMA

            // ---- h @ U^T partials: wave (g,kh), 2 m-tiles x 2 n-tiles ----
            f32x4 acc[2][2] = {};
            const int swz = (lr & 7) << 4;
#pragma unroll
            for (int s = 0; s < 16; ++s) {
                int kb = (kh * 512 + s * 32 + lg * 8) * 2;
                short8 a0 = *(const short8*)(shc + lr * 2048 + (kb ^ swz));
                short8 a1 = *(const short8*)(shc + (16 + lr) * 2048 + (kb ^ swz));
#pragma unroll
                for (int n = 0; n < 2; ++n) {
                    acc[0][n] = __builtin_amdgcn_mfma_f32_16x16x32_bf16(a0, ureg[n][s], acc[0][n], 0, 0, 0);
                    acc[1][n] = __builtin_amdgcn_mfma_f32_16x16x32_bf16(a1, ureg[n][s], acc[1][n], 0, 0, 0);
                }
            }
            // partials -> gpart (b-index XOR-swizzled; 4 consecutive rows per b128)
#pragma unroll
            for (int m = 0; m < 2; ++m)
#pragma unroll
                for (int n = 0; n < 2; ++n) {
                    int col = n * 16 + lr;
                    int bb  = (m * 16 + lg * 4) ^ ((col & 7) << 2);
                    *(f32x4*)&gpart[kh][g][col][bb] = acc[m][n];
                }
        } else {
            prefetch_wx(1, 1);
        }
        __syncthreads();                                      // B3

        // ---- pointwise: gates = partial0 + partial1 + wx + b_u ----
        float hv[2], cv[2];
        uint wxu[4];
#pragma unroll
        for (int g2 = 0; g2 < 4; ++g2)
            wxu[g2] = *(const uint*)((const ushort*)swx + (t & 1) * 4096 + bp * 128 + g2 * 32 + cp);
#pragma unroll
        for (int cc = 0; cc < 2; ++cc) {
            int col = cp + cc;
            float gv[4];
#pragma unroll
            for (int g2 = 0; g2 < 4; ++g2) {
                float s = bf2f((ushort)(cc ? (wxu[g2] >> 16) : (wxu[g2] & 0xffffu))) + bu2[g2][cc];
                if (t > 0) {
                    int bb = bp ^ ((col & 7) << 2);
                    s += gpart[0][g2][col][bb] + gpart[1][g2][col][bb];
                }
                gv[g2] = s;
            }
            float si = 1.f / (1.f + __expf(-gv[0]));
            float sf = 1.f / (1.f + __expf(-gv[1]));
            float tg = 2.f / (1.f + __expf(-2.f * gv[2])) - 1.f;
            float so = 1.f / (1.f + __expf(-gv[3]));
            float c  = sf * creg[cc] + si * tg;
            creg[cc] = c;
            cv[cc]   = c;
            hv[cc]   = so * fmaxf(c, 0.f);
        }
        uint hp = (uint)f2bf(hv[0]) | ((uint)f2bf(hv[1]) << 16);
        __hip_atomic_store(&hbuf[(t & 1) * 16384 + bp * 512 + (j * 32 + cp) / 2], hp,
                           __ATOMIC_RELAXED, __HIP_MEMORY_SCOPE_AGENT);

        __syncthreads();          // B4: all waves' h stores vmcnt-drained (coherence point)
        if (tid == 0)
            __hip_atomic_fetch_add(cnt, 1u, __ATOMIC_RELAXED, __HIP_MEMORY_SCOPE_AGENT);

        // ---- stream outputs (off the inter-WG critical path) ----
        size_t ob = ((size_t)bp * T_ + t) * H_ + j * 32 + cp;
        unsigned long long hq = (unsigned long long)__builtin_bit_cast(unsigned, hv[0])
                              | ((unsigned long long)__builtin_bit_cast(unsigned, hv[1]) << 32);
        unsigned long long cq = (unsigned long long)__builtin_bit_cast(unsigned, cv[0])
                              | ((unsigned long long)__builtin_bit_cast(unsigned, cv[1]) << 32);
        __builtin_nontemporal_store(hq, (unsigned long long*)(hs + ob));
        __builtin_nontemporal_store(cq, (unsigned long long*)(cs + ob));
    }
}

// ------------------------------- launcher --------------------------------------
extern "C" void kernel_launch(void* const* d_in, const int* in_sizes, int n_in,
                              void* d_out, int out_size, void* d_ws, size_t ws_size,
                              hipStream_t stream)
{
    const float* x  = (const float*)d_in[0];   // [B,T,I]
    const float* W  = (const float*)d_in[1];   // [4H,I]
    const float* bw = (const float*)d_in[2];   // [4H]
    const float* Uf = (const float*)d_in[3];   // [4H,H]
    const float* bu = (const float*)d_in[4];   // [4H]

    float* out = (float*)d_out;
    float* hs  = out;                          // [B,T,H]
    float* cs  = out + (size_t)B_ * T_ * H_;   // [B,T,H]

    char* ws = (char*)d_ws;
    ushort*   x_bf  = (ushort*)ws;                           // 32 MiB @ 0
    ushort*   W_bf  = (ushort*)(ws + 33554432);              // 8 MiB
    ushort*   U_bf  = (ushort*)(ws + 41943040);              // 8 MiB
    ushort*   wx_bf = (ushort*)(ws + 50331648);              // 128 MiB [T][B][4H]
    uint*     hbuf  = (uint*)(ws + 184549376);               // 128 KiB [2][32][512]
    unsigned* cnt   = (unsigned*)(ws + 184680448);           // 256 B

    hipMemsetAsync(cnt, 0, 256, stream);   // barrier counter must start at 0

    cvt_bf16<<<2048, 256, 0, stream>>>(x,  x_bf, B_ * T_ * I_);
    cvt_bf16<<<1024, 256, 0, stream>>>(W,  W_bf, G4_ * I_);
    cvt_bf16<<<1024, 256, 0, stream>>>(Uf, U_bf, G4_ * H_);

    dim3 grid(G4_ / BN, (B_ * T_) / BM);   // 32 x 128
    gemm_bt<<<grid, 256, 0, stream>>>(x_bf, W_bf, bw, wx_bf, B_ * T_, G4_, I_);

    lstm_persist<<<NWG, 512, 0, stream>>>(wx_bf, U_bf, bu, hbuf, hs, cs, cnt);
}

// Round 8
// 3845.880 us; speedup vs baseline: 1.2123x; 1.0448x over previous
//
#include <hip/hip_runtime.h>
#include <hip/hip_bf16.h>

// Problem constants (LSTM_Layer_48601849922172)
#define B_  32
#define T_  512
#define I_  1024
#define H_  1024
#define G4_ 4096   // 4*H
#define NWG 32     // persistent workgroups

typedef short short8 __attribute__((ext_vector_type(8)));   // 8 bf16 in 4 VGPRs
typedef float f32x4  __attribute__((ext_vector_type(4)));

__device__ __forceinline__ ushort f2bf(float f) {
    unsigned u = __builtin_bit_cast(unsigned, f);
    u += 0x7fffu + ((u >> 16) & 1u);   // RNE
    return (ushort)(u >> 16);
}
__device__ __forceinline__ float bf2f(ushort u) {
    unsigned x = ((unsigned)u) << 16;
    return __builtin_bit_cast(float, x);
}

__device__ __forceinline__ void async16(const void* g, void* l) {
    __builtin_amdgcn_global_load_lds((const __attribute__((address_space(1))) void*)g,
                                     (__attribute__((address_space(3))) void*)l,
                                     16, 0, 0);
}

// ---------------- f32 -> bf16 conversion (vectorized, grid-stride) -------------
__global__ void cvt_bf16(const float* __restrict__ in, ushort* __restrict__ out, int n) {
    int stride = gridDim.x * blockDim.x;
    for (int i = blockIdx.x * blockDim.x + threadIdx.x; i * 4 < n; i += stride) {
        float4 v = reinterpret_cast<const float4*>(in)[i];
        ushort4 o;
        o.x = f2bf(v.x); o.y = f2bf(v.y); o.z = f2bf(v.z); o.w = f2bf(v.w);
        reinterpret_cast<ushort4*>(out)[i] = o;
    }
}

// ---------------- wx = x @ W^T + b_w : m97-style 128x128x32 MFMA GEMM ----------
// A: [M][K] bf16 (M = B*T, row = b*T + t), Bm: [N][K] bf16 (W, B^T layout).
// Output: bf16, remapped to [T][B][4H] so each step's slice is contiguous.
#define BM 128
#define BN 128
#define BK 32

__global__ __launch_bounds__(256) void gemm_bt(
    const ushort* __restrict__ A, const ushort* __restrict__ Bm,
    const float* __restrict__ bias, ushort* __restrict__ C,
    int M, int N, int K)
{
    __shared__ ushort sA[2][BM * BK];
    __shared__ ushort sB[2][BN * BK];

    const int tid  = threadIdx.x;
    const int m0   = blockIdx.y * BM;
    const int n0   = blockIdx.x * BN;
    const int lane = tid & 63, wid = tid >> 6;
    const int wm   = (wid >> 1) * 64, wn = (wid & 1) * 64;
    const int lr   = lane & 15, lg = lane >> 4;

    f32x4 acc[4][4] = {};

    auto stage = [&](int buf, int kt) {
        const int k0 = kt * BK;
#pragma unroll
        for (int i = 0; i < 2; ++i) {
            int c = tid + i * 256;                 // 512 chunks of 16B per tile
            const ushort* ga = A  + (size_t)(m0 + (c >> 2)) * K + k0 + (c & 3) * 8;
            async16(ga, &sA[buf][c * 8]);
            const ushort* gb = Bm + (size_t)(n0 + (c >> 2)) * K + k0 + (c & 3) * 8;
            async16(gb, &sB[buf][c * 8]);
        }
    };

    stage(0, 0);
    __syncthreads();

    const int nk = K / BK;
    int buf = 0;
    for (int kt = 0; kt < nk; ++kt) {
        if (kt + 1 < nk) stage(buf ^ 1, kt + 1);
        short8 af[4], bfr[4];
#pragma unroll
        for (int i = 0; i < 4; ++i)
            af[i]  = *reinterpret_cast<const short8*>(&sA[buf][(wm + i * 16 + lr) * BK + lg * 8]);
#pragma unroll
        for (int i = 0; i < 4; ++i)
            bfr[i] = *reinterpret_cast<const short8*>(&sB[buf][(wn + i * 16 + lr) * BK + lg * 8]);
#pragma unroll
        for (int mi = 0; mi < 4; ++mi)
#pragma unroll
            for (int ni = 0; ni < 4; ++ni)
                acc[mi][ni] = __builtin_amdgcn_mfma_f32_16x16x32_bf16(af[mi], bfr[ni], acc[mi][ni], 0, 0, 0);
        __syncthreads();
        buf ^= 1;
    }

    // C/D layout (m89-verified): col = lane&15, row = (lane>>4)*4 + reg
#pragma unroll
    for (int mi = 0; mi < 4; ++mi) {
#pragma unroll
        for (int ni = 0; ni < 4; ++ni) {
            int col = n0 + wn + ni * 16 + lr;
            float bv = bias[col];
#pragma unroll
            for (int r = 0; r < 4; ++r) {
                int row = m0 + wm + mi * 16 + lg * 4 + r;   // = b*T + t
                int b = row >> 9, t = row & (T_ - 1);
                C[((size_t)t * B_ + b) * G4_ + col] = f2bf(acc[mi][ni][r] + bv);
            }
        }
    }
}

// ---------------- persistent recurrence -----------------------------------------
// 32 WGs x 512 threads. WG j owns h-cols [j*32, j*32+32) for all 4 gates.
// Wave w: gate g = w&3, k-half kh = w>>2.
// __launch_bounds__(512,1): 2 waves/SIMD -> 256-VGPR budget so ureg (128 VGPRs)
// stays register-resident (round-7's (512,2) forced a 128-cap -> scratch spill).
// Cross-step h exchange: relaxed AGENT-scope atomics. hs/cs: nontemporal stores
// after the arrive. wx prefetched at loop top so HBM latency hides under poll.
__global__ __launch_bounds__(512, 1) void lstm_persist(
    const ushort* __restrict__ wx,     // [T][B][4H] bf16
    const ushort* __restrict__ U_bf,   // [4H][H] bf16
    const float*  __restrict__ b_u,    // [4H]
    uint*   __restrict__ hbuf,         // [2][32][512] uint (2 bf16 packed) ping-pong
    float*  __restrict__ hs,           // [B][T][H]
    float*  __restrict__ cs,           // [B][T][H]
    unsigned* cnt)                     // grid barrier counter (pre-zeroed)
{
    const int tid  = threadIdx.x;
    const int lane = tid & 63, wid = tid >> 6;
    const int lr   = lane & 15, lg = lane >> 4;
    const int g    = wid & 3, kh = wid >> 2;
    const int j    = blockIdx.x;

    // ---- U fragments -> VGPRs (loop-invariant; restrict proves no-alias) ----
    // wave (g,kh), lane (lr,lg): frag (n,s) = U[g*1024+j*32+n*16+lr][kh*512+s*32+lg*8 ..+8]
    short8 ureg[2][16];
#pragma unroll
    for (int n = 0; n < 2; ++n)
#pragma unroll
        for (int s = 0; s < 16; ++s)
            ureg[n][s] = *(const short8*)(U_bf + (size_t)(g * 1024 + j * 32 + n * 16 + lr) * 1024
                                          + kh * 512 + s * 32 + lg * 8);

    __shared__ ushort sh[32 * 1024];        // 64KB h tile, XOR-swizzled rows
    __shared__ float  gpart[2][4][32][32];  // 32KB [kh][g][col][b^swz] partial gates
    __shared__ ushort swx[2][4096];         // 2x8KB wx tile [buf][b][g][32 cols]
    char* shc = (char*)sh;

    // pointwise mapping: thread -> (batch bp, col pair cp, cp+1); c-state in regs
    const int bp = tid >> 4, cp = (tid & 15) * 2;
    float creg[2] = {0.f, 0.f};
    float bu2[4][2];
#pragma unroll
    for (int g2 = 0; g2 < 4; ++g2) {
        bu2[g2][0] = b_u[g2 * 1024 + j * 32 + cp];
        bu2[g2][1] = b_u[g2 * 1024 + j * 32 + cp + 1];
    }

    // wx prefetch: 8KB/WG/step -> LDS via global_load_lds (linear dest)
    auto prefetch_wx = [&](int tt, int buf) {
        int b = tid >> 4, g2 = (tid >> 2) & 3, q = tid & 3;
        const ushort* src = wx + ((size_t)tt * 32 + b) * 4096 + g2 * 1024 + j * 32 + q * 8;
        async16(src, (char*)swx + buf * 8192 + tid * 16);
    };

    prefetch_wx(0, 0);

    for (int t = 0; t < T_; ++t) {
        // ---- prefetch next step's wx early: latency hides under poll+stage ----
        {
            int tn = (t + 1 < T_) ? t + 1 : t;
            prefetch_wx(tn, (t + 1) & 1);
        }

        if (t > 0) {
            // ---- wait for all WGs to finish step t-1 ----
            if (tid == 0) {
                while (__hip_atomic_load(cnt, __ATOMIC_RELAXED, __HIP_MEMORY_SCOPE_AGENT)
                       < (unsigned)(NWG * t))
                    __builtin_amdgcn_s_sleep(1);
            }
            __syncthreads();                                  // B1

            // ---- stage h_{t-1}: coherent 8B loads -> swizzled LDS ----
            const unsigned long long* hsrc =
                (const unsigned long long*)(hbuf + ((t + 1) & 1) * 16384);
#pragma unroll
            for (int i = 0; i < 16; ++i) {
                int idx = i * 512 + tid;
                unsigned long long v = __hip_atomic_load(&hsrc[idx],
                    __ATOMIC_RELAXED, __HIP_MEMORY_SCOPE_AGENT);
                int o = idx * 8, row = o >> 11, inner = o & 2047;
                *(unsigned long long*)(shc + row * 2048 + (inner ^ ((row & 7) << 4))) = v;
            }
            __syncthreads();                                  // B2

            // ---- h @ U^T partials: wave (g,kh), 2 m-tiles x 2 n-tiles ----
            f32x4 acc[2][2] = {};
            const int swz = (lr & 7) << 4;
#pragma unroll
            for (int s = 0; s < 16; ++s) {
                int kb = (kh * 512 + s * 32 + lg * 8) * 2;
                short8 a0 = *(const short8*)(shc + lr * 2048 + (kb ^ swz));
                short8 a1 = *(const short8*)(shc + (16 + lr) * 2048 + (kb ^ swz));
#pragma unroll
                for (int n = 0; n < 2; ++n) {
                    acc[0][n] = __builtin_amdgcn_mfma_f32_16x16x32_bf16(a0, ureg[n][s], acc[0][n], 0, 0, 0);
                    acc[1][n] = __builtin_amdgcn_mfma_f32_16x16x32_bf16(a1, ureg[n][s], acc[1][n], 0, 0, 0);
                }
            }
            // partials -> gpart (b-index XOR-swizzled; 4 consecutive rows per b128)
#pragma unroll
            for (int m = 0; m < 2; ++m)
#pragma unroll
                for (int n = 0; n < 2; ++n) {
                    int col = n * 16 + lr;
                    int bb  = (m * 16 + lg * 4) ^ ((col & 7) << 2);
                    *(f32x4*)&gpart[kh][g][col][bb] = acc[m][n];
                }
        }
        __syncthreads();                                      // B3

        // ---- pointwise: gates = partial0 + partial1 + wx + b_u ----
        float hv[2], cv[2];
        uint wxu[4];
#pragma unroll
        for (int g2 = 0; g2 < 4; ++g2)
            wxu[g2] = *(const uint*)((const ushort*)swx + (t & 1) * 4096 + bp * 128 + g2 * 32 + cp);
#pragma unroll
        for (int cc = 0; cc < 2; ++cc) {
            int col = cp + cc;
            float gv[4];
#pragma unroll
            for (int g2 = 0; g2 < 4; ++g2) {
                float s = bf2f((ushort)(cc ? (wxu[g2] >> 16) : (wxu[g2] & 0xffffu))) + bu2[g2][cc];
                if (t > 0) {
                    int bb = bp ^ ((col & 7) << 2);
                    s += gpart[0][g2][col][bb] + gpart[1][g2][col][bb];
                }
                gv[g2] = s;
            }
            float si = 1.f / (1.f + __expf(-gv[0]));
            float sf = 1.f / (1.f + __expf(-gv[1]));
            float tg = 2.f / (1.f + __expf(-2.f * gv[2])) - 1.f;
            float so = 1.f / (1.f + __expf(-gv[3]));
            float c  = sf * creg[cc] + si * tg;
            creg[cc] = c;
            cv[cc]   = c;
            hv[cc]   = so * fmaxf(c, 0.f);
        }
        uint hp = (uint)f2bf(hv[0]) | ((uint)f2bf(hv[1]) << 16);
        __hip_atomic_store(&hbuf[(t & 1) * 16384 + bp * 512 + (j * 32 + cp) / 2], hp,
                           __ATOMIC_RELAXED, __HIP_MEMORY_SCOPE_AGENT);

        __syncthreads();          // B4: all waves' h stores vmcnt-drained (coherence point)
        if (tid == 0)
            __hip_atomic_fetch_add(cnt, 1u, __ATOMIC_RELAXED, __HIP_MEMORY_SCOPE_AGENT);

        // ---- stream outputs (off the inter-WG critical path) ----
        size_t ob = ((size_t)bp * T_ + t) * H_ + j * 32 + cp;
        unsigned long long hq = (unsigned long long)__builtin_bit_cast(unsigned, hv[0])
                              | ((unsigned long long)__builtin_bit_cast(unsigned, hv[1]) << 32);
        unsigned long long cq = (unsigned long long)__builtin_bit_cast(unsigned, cv[0])
                              | ((unsigned long long)__builtin_bit_cast(unsigned, cv[1]) << 32);
        __builtin_nontemporal_store(hq, (unsigned long long*)(hs + ob));
        __builtin_nontemporal_store(cq, (unsigned long long*)(cs + ob));
    }
}

// ------------------------------- launcher --------------------------------------
extern "C" void kernel_launch(void* const* d_in, const int* in_sizes, int n_in,
                              void* d_out, int out_size, void* d_ws, size_t ws_size,
                              hipStream_t stream)
{
    const float* x  = (const float*)d_in[0];   // [B,T,I]
    const float* W  = (const float*)d_in[1];   // [4H,I]
    const float* bw = (const float*)d_in[2];   // [4H]
    const float* Uf = (const float*)d_in[3];   // [4H,H]
    const float* bu = (const float*)d_in[4];   // [4H]

    float* out = (float*)d_out;
    float* hs  = out;                          // [B,T,H]
    float* cs  = out + (size_t)B_ * T_ * H_;   // [B,T,H]

    char* ws = (char*)d_ws;
    ushort*   x_bf  = (ushort*)ws;                           // 32 MiB @ 0
    ushort*   W_bf  = (ushort*)(ws + 33554432);              // 8 MiB
    ushort*   U_bf  = (ushort*)(ws + 41943040);              // 8 MiB
    ushort*   wx_bf = (ushort*)(ws + 50331648);              // 128 MiB [T][B][4H]
    uint*     hbuf  = (uint*)(ws + 184549376);               // 128 KiB [2][32][512]
    unsigned* cnt   = (unsigned*)(ws + 184680448);           // 256 B

    hipMemsetAsync(cnt, 0, 256, stream);   // barrier counter must start at 0

    cvt_bf16<<<2048, 256, 0, stream>>>(x,  x_bf, B_ * T_ * I_);
    cvt_bf16<<<1024, 256, 0, stream>>>(W,  W_bf, G4_ * I_);
    cvt_bf16<<<1024, 256, 0, stream>>>(Uf, U_bf, G4_ * H_);

    dim3 grid(G4_ / BN, (B_ * T_) / BM);   // 32 x 128
    gemm_bt<<<grid, 256, 0, stream>>>(x_bf, W_bf, bw, wx_bf, B_ * T_, G4_, I_);

    lstm_persist<<<NWG, 512, 0, stream>>>(wx_bf, U_bf, bu, hbuf, hs, cs, cnt);
}